// Round 2
// baseline (348.509 us; speedup 1.0000x reference)
//
#include <hip/hip_runtime.h>

#define HID 10
#define STEPS 512

typedef __attribute__((ext_vector_type(2))) float v2f;

// broadcast lane ((lane&0x10)|F) within each 32-lane half -> all lanes of each 16-group
// (used only in the one-time t=0 peel now)
template<int F>
static __device__ __forceinline__ float swz(float v) {
    return __int_as_float(__builtin_amdgcn_ds_swizzle(__float_as_int(v), (F << 5) | 0x10));
}

// DPP row_ror:J — rotate within each 16-lane row on the VALU pipe (no LDS).
// Direction convention is irrelevant: weight tables are built from a
// self-calibrated source-index probe using the SAME ctrl (irot on lane id).
template<int J>
static __device__ __forceinline__ float frot(float v) {
    return __int_as_float(__builtin_amdgcn_update_dpp(
        0, __float_as_int(v), 0x120 + J, 0xF, 0xF, true));
}
template<int J>
static __device__ __forceinline__ int irot(int v) {
    return __builtin_amdgcn_update_dpp(0, v, 0x120 + J, 0xF, 0xF, true);
}

// Lane-parallel fused GRU decoder, 1 feature per lane, 4 batches per wave.
//   batch = blockIdx*4 + (lane>>4); f = lane&15 (f>=10: zero-padded, stores masked)
// Per-step h broadcast: 15 independent DPP row-rotations (VALU, ~4cy) instead of
// 10 ds_swizzle (LDS pipe shared by 4 SIMDs/CU, ~60-120cy) — v0 was latency-bound
// on the DS pipe (VALUBusy 61%). Dots are 16-term (6 zero-weighted).
// PIPELINED STORE: o_t = l1(h_{t+1}); iteration t stores o_{t-1} from the same
// rh[] used for the gates (free), epilogue stores o_511. (Round-1 bug: stored
// l1(h_t) as o_t — one-timestep shift, absmax ~1.0.)
__global__ __launch_bounds__(64, 2) void gru_decoder_kernel(
    const float* __restrict__ hidden, const float* __restrict__ w_ih,
    const float* __restrict__ w_hh, const float* __restrict__ b_ih,
    const float* __restrict__ b_hh, const float* __restrict__ l1_w,
    const float* __restrict__ l1_b, const float* __restrict__ l2_w,
    const float* __restrict__ l2_b, float* __restrict__ out)
{
    __shared__ float sWx[640];   // l2_w @ l1_w (64x10)
    __shared__ float sbx[64];    // l2_w @ l1_b + l2_b
    __shared__ float sWgi[300];  // w_ih @ Wx (30x10)
    __shared__ float sbgi[30];   // b_ih + w_ih @ bx
    __shared__ float sWhh[300];  // w_hh copy (t=0 peel + weight build)

    const int lane = threadIdx.x;
    const int f    = lane & 15;
    const int b    = blockIdx.x * 4 + (lane >> 4);
    const bool ok  = (f < HID);
    const int fi   = ok ? f : 0;          // clamped index for safe reads

    // ---- preamble: fused weights (fp32, cooperative) ----
    for (int e = lane; e < 640; e += 64) {
        int i = e / 10, j = e - i * 10;
        float acc = 0.f;
        #pragma unroll
        for (int k = 0; k < 10; ++k) acc += l2_w[i * 10 + k] * l1_w[k * 10 + j];
        sWx[e] = acc;
    }
    {
        float acc = l2_b[lane];
        #pragma unroll
        for (int k = 0; k < 10; ++k) acc += l2_w[lane * 10 + k] * l1_b[k];
        sbx[lane] = acc;
    }
    for (int e = lane; e < 300; e += 64) sWhh[e] = w_hh[e];
    __syncthreads();
    for (int e = lane; e < 300; e += 64) {
        int m = e / 10, j = e - m * 10;
        float acc = 0.f;
        for (int k = 0; k < 64; ++k) acc += w_ih[m * 64 + k] * sWx[k * 10 + j];
        sWgi[e] = acc;
    }
    if (lane < 30) {
        float acc = b_ih[lane];
        for (int k = 0; k < 64; ++k) acc += w_ih[lane * 64 + k] * sbx[k];
        sbgi[lane] = acc;
    }
    __syncthreads();

    const float LOG2E = 1.4426950408889634f;
    const float S2    = 2.f * LOG2E;

    // ---- self-calibrated rotation source indices (within each 16-row) ----
    int sidx[16];
    sidx[0]  = f;
    sidx[1]  = irot<1>(f);   sidx[2]  = irot<2>(f);   sidx[3]  = irot<3>(f);
    sidx[4]  = irot<4>(f);   sidx[5]  = irot<5>(f);   sidx[6]  = irot<6>(f);
    sidx[7]  = irot<7>(f);   sidx[8]  = irot<8>(f);   sidx[9]  = irot<9>(f);
    sidx[10] = irot<10>(f);  sidx[11] = irot<11>(f);  sidx[12] = irot<12>(f);
    sidx[13] = irot<13>(f);  sidx[14] = irot<14>(f);  sidx[15] = irot<15>(f);

    // ---- per-lane rotated weight tables (16 terms; zeros for padded sources) ----
    v2f wrz[16], wnn[16];
    float wo[16];
    #pragma unroll
    for (int j = 0; j < 16; ++j) {
        int s   = sidx[j];
        bool va = ok && (s < HID);
        int sc  = (s < HID) ? s : 0;
        float grz_r = -(sWgi[fi * 10 + sc] + sWhh[fi * 10 + sc]) * LOG2E;
        float grz_z = -(sWgi[(10 + fi) * 10 + sc] + sWhh[(10 + fi) * 10 + sc]) * LOG2E;
        float gni   = sWgi[(20 + fi) * 10 + sc] * S2;
        float gnh   = sWhh[(20 + fi) * 10 + sc] * S2;
        wrz[j] = va ? v2f{grz_r, grz_z} : v2f{0.f, 0.f};
        wnn[j] = va ? v2f{gni, gnh}     : v2f{0.f, 0.f};
        wo[j]  = va ? l1_w[fi * 10 + sc] : 0.f;
    }

    const v2f brz = ok ? v2f{-(sbgi[fi] + b_hh[fi]) * LOG2E,
                             -(sbgi[10 + fi] + b_hh[10 + fi]) * LOG2E}
                       : v2f{0.f, 0.f};
    const v2f bnn = ok ? v2f{sbgi[20 + fi] * S2, b_hh[20 + fi] * S2} : v2f{0.f, 0.f};
    const float bo = ok ? l1_b[fi] : 0.f;
    // t=0 peel biases (gi = b_ih only)
    const v2f brz0 = ok ? v2f{-(b_ih[fi] + b_hh[fi]) * LOG2E,
                              -(b_ih[10 + fi] + b_hh[10 + fi]) * LOG2E}
                        : v2f{0.f, 0.f};
    const float bni0 = ok ? b_ih[20 + fi] * S2 : 0.f;

    // ---- initial h (one feature per lane; f>=10 stays exactly 0) ----
    float h = ok ? hidden[(size_t)b * HID + f] : 0.f;

    float* pb = out + (size_t)b * (STEPS * HID) + (size_t)(STEPS - 1) * HID + f;

    // ---- t = 0 peeled: gi = b_ih only (x_0 = 0); raw w_hh dots from LDS ----
    // Produces h1. Its output o_0 = l1(h1) is stored by the first loop iteration.
    {
        float ha[10];
        ha[0] = swz<0>(h); ha[1] = swz<1>(h); ha[2] = swz<2>(h);
        ha[3] = swz<3>(h); ha[4] = swz<4>(h); ha[5] = swz<5>(h);
        ha[6] = swz<6>(h); ha[7] = swz<7>(h); ha[8] = swz<8>(h);
        ha[9] = swz<9>(h);
        float pr = 0.f, pz = 0.f, ph = 0.f;
        #pragma unroll
        for (int k = 0; k < 10; ++k) {
            pr += sWhh[fi * 10 + k] * ha[k];
            pz += sWhh[(10 + fi) * 10 + k] * ha[k];
            ph += sWhh[(20 + fi) * 10 + k] * ha[k];
        }
        float vr = brz0.x - pr * LOG2E;
        float vz = brz0.y - pz * LOG2E;
        float r = __builtin_amdgcn_rcpf(1.f + __builtin_amdgcn_exp2f(vr));
        float z = __builtin_amdgcn_rcpf(1.f + __builtin_amdgcn_exp2f(vz));
        float y = bni0 + r * (ph * S2 + bnn.y);
        float n = 1.f - 2.f * __builtin_amdgcn_rcpf(1.f + __builtin_amdgcn_exp2f(y));
        h = ok ? (n + z * (h - n)) : 0.f;
    }

    // ---- t = 1 .. 511 : rotation broadcast; iteration t stores o_{t-1} ----
    #pragma unroll 1
    for (int t = 1; t < STEPS; ++t) {
        float rh[16];
        rh[0]  = h;
        rh[1]  = frot<1>(h);   rh[2]  = frot<2>(h);   rh[3]  = frot<3>(h);
        rh[4]  = frot<4>(h);   rh[5]  = frot<5>(h);   rh[6]  = frot<6>(h);
        rh[7]  = frot<7>(h);   rh[8]  = frot<8>(h);   rh[9]  = frot<9>(h);
        rh[10] = frot<10>(h);  rh[11] = frot<11>(h);  rh[12] = frot<12>(h);
        rh[13] = frot<13>(h);  rh[14] = frot<14>(h);  rh[15] = frot<15>(h);

        v2f a0 = brz, n0 = bnn;
        v2f a1 = {0.f, 0.f}, n1 = {0.f, 0.f};
        float o0 = bo, o1 = 0.f;
        #pragma unroll
        for (int j = 0; j < 8; ++j) {
            v2f hj = {rh[j], rh[j]};
            a0 += wrz[j] * hj;
            n0 += wnn[j] * hj;
            o0 = __builtin_fmaf(wo[j], rh[j], o0);
        }
        #pragma unroll
        for (int j = 8; j < 16; ++j) {
            v2f hj = {rh[j], rh[j]};
            a1 += wrz[j] * hj;
            n1 += wnn[j] * hj;
            o1 = __builtin_fmaf(wo[j], rh[j], o1);
        }
        v2f arz = a0 + a1;
        v2f ann = n0 + n1;
        float o = o0 + o1;          // = l1(h_t) = o_{t-1}

        float r = __builtin_amdgcn_rcpf(1.f + __builtin_amdgcn_exp2f(arz.x));
        float z = __builtin_amdgcn_rcpf(1.f + __builtin_amdgcn_exp2f(arz.y));
        float zh  = z * h;        // off the n-path: issue early
        float omz = 1.f - z;
        float y = __builtin_fmaf(r, ann.y, ann.x);
        float n = 1.f - 2.f * __builtin_amdgcn_rcpf(1.f + __builtin_amdgcn_exp2f(y));
        h = __builtin_fmaf(n, omz, zh);   // == n + z*(h-n); padded lanes stay 0

        if (ok) pb[0] = o;                 // store o_{t-1} (position STEPS-t)
        pb -= HID;
    }

    // ---- epilogue: o_511 = l1(h_512) at position 0 ----
    {
        float rh[16];
        rh[0]  = h;
        rh[1]  = frot<1>(h);   rh[2]  = frot<2>(h);   rh[3]  = frot<3>(h);
        rh[4]  = frot<4>(h);   rh[5]  = frot<5>(h);   rh[6]  = frot<6>(h);
        rh[7]  = frot<7>(h);   rh[8]  = frot<8>(h);   rh[9]  = frot<9>(h);
        rh[10] = frot<10>(h);  rh[11] = frot<11>(h);  rh[12] = frot<12>(h);
        rh[13] = frot<13>(h);  rh[14] = frot<14>(h);  rh[15] = frot<15>(h);
        float o0 = bo, o1 = 0.f;
        #pragma unroll
        for (int j = 0; j < 8; ++j)  o0 = __builtin_fmaf(wo[j], rh[j], o0);
        #pragma unroll
        for (int j = 8; j < 16; ++j) o1 = __builtin_fmaf(wo[j], rh[j], o1);
        if (ok) pb[0] = o0 + o1;
    }
}

extern "C" void kernel_launch(void* const* d_in, const int* in_sizes, int n_in,
                              void* d_out, int out_size, void* d_ws, size_t ws_size,
                              hipStream_t stream) {
    (void)in_sizes; (void)n_in; (void)d_ws; (void)ws_size; (void)out_size;
    dim3 grid(2048), block(64);   // 4 batches/wave, 2048 waves -> 2 waves per SIMD
    gru_decoder_kernel<<<grid, block, 0, stream>>>(
        (const float*)d_in[0], (const float*)d_in[1], (const float*)d_in[2],
        (const float*)d_in[3], (const float*)d_in[4], (const float*)d_in[5],
        (const float*)d_in[6], (const float*)d_in[7], (const float*)d_in[8],
        (float*)d_out);
}